// Round 8
// baseline (624.437 us; speedup 1.0000x reference)
//
#include <hip/hip_runtime.h>
#include <hip/hip_bf16.h>

#define NROWS 6272
#define MROWS 32768
#define DDIM  384
#define NB    8
#define PPB   784
#define BN    128
#define BMT   128
#define MSPLIT 16
#define MC    (MROWS / MSPLIT)     // 2048
#define MTILES (MC / BMT)          // 16
#define NSTEPS (MTILES * 12)       // 192 K-steps of 32
#define PSW   (MSPLIT * 2)         // 32 partial slots per row (chunk x wm-half)
#define KNN   9
#define TSEG  16
#define TOPT  3
#define NRESC (NB * TOPT)          // 24

typedef float f32x4 __attribute__((ext_vector_type(4)));
typedef short bf16x8 __attribute__((ext_vector_type(8)));

__device__ __forceinline__ unsigned short f2bf(float f) {
  union { float f; unsigned int u; } c; c.f = f;
  unsigned int u = c.u + 0x7FFFu + ((c.u >> 16) & 1u);  // RNE
  return (unsigned short)(u >> 16);
}
__device__ __forceinline__ unsigned int pk2(float a, float b) {
  return (unsigned int)f2bf(a) | ((unsigned int)f2bf(b) << 16);
}
__device__ __forceinline__ float wredsum(float v) {
#pragma unroll
  for (int m = 32; m; m >>= 1) v += __shfl_xor(v, m, 64);
  return v;
}
__device__ __forceinline__ void glds16(const void* g, void* l) {
  __builtin_amdgcn_global_load_lds(
      (const __attribute__((address_space(1))) unsigned int*)g,
      (__attribute__((address_space(3))) unsigned int*)l, 16, 0, 0);
}

// ---------------------------------------------------------------- fp32 -> bf16 copy
__global__ __launch_bounds__(256) void cvt_bf16_kernel(
    const float* __restrict__ src, unsigned short* __restrict__ dst) {
  const int i = blockIdx.x * 256 + threadIdx.x;  // 8 elems per thread
  const float4 a = ((const float4*)src)[i * 2];
  const float4 b = ((const float4*)src)[i * 2 + 1];
  uint4 o = { pk2(a.x, a.y), pk2(a.z, a.w), pk2(b.x, b.y), pk2(b.z, b.w) };
  ((uint4*)dst)[i] = o;
}

// ---------------------------------------------------------------- row norms (exact fp32)
// one wave per row; works for bank (32768) and emb (6272)
__global__ __launch_bounds__(256) void rownorm_kernel(
    const float* __restrict__ src, float* __restrict__ nrm) {
  const int wave = threadIdx.x >> 6, lane = threadIdx.x & 63;
  const int m = blockIdx.x * 4 + wave;
  const float* y = src + (size_t)m * DDIM;
  float s = 0.f;
#pragma unroll
  for (int j = 0; j < 6; ++j) { float v = y[lane + 64 * j]; s = fmaf(v, v, s); }
  s = wredsum(s);
  if (lane == 0) nrm[m] = s;
}

// ------------------------------------------------- hot: bf16 MFMA per-chunk min
// grid 784; ms = bid&15 (XCD-affine, B chunk L2-resident). Double-buffered LDS,
// prefetch(st+1) issued before compute(st); ONE __syncthreads per step.
// Emits rm = min(ynorm - 2*dot) per (row, chunk, wm-half); xnorm added in ps_reduce
// (FIX R7->R8: the ||x||^2 term was dropped in the R5 restructure -> absmax 12.8).
__global__ __launch_bounds__(256) void dist_min_kernel(
    const unsigned short* __restrict__ embbf, const unsigned short* __restrict__ bankbf,
    const float* __restrict__ ynorm, float* __restrict__ psPart) {
  __shared__ unsigned short Al[2][4096];   // [buf][128 rows x 32 bf16] 64B rows
  __shared__ unsigned short Bl[2][4096];
  __shared__ float ynLds[MC];

  const int bid = blockIdx.x;
  const int ms = bid & (MSPLIT - 1);
  const int bn = bid >> 4;
  const int t = threadIdx.x;
  const int lane = t & 63;
  const int wave = t >> 6;
  const int wn = wave >> 1, wm = wave & 1;
  const int l15 = lane & 15, l4 = lane >> 4;

  for (int i = t; i < MC; i += 256) ynLds[i] = ynorm[ms * MC + i];

  // staging sources (global_load_lds: lds dest = uniform base + lane*16B)
  const int seg0 = wave * 2, seg1 = seg0 + 1;
  const int sRow = lane >> 2;
  const int sColB = (lane & 3) * 16;  // bytes
  const char* aG0 = (const char*)embbf + ((size_t)(bn * BN + seg0 * 16 + sRow)) * 768 + sColB;
  const char* aG1 = (const char*)embbf + ((size_t)(bn * BN + seg1 * 16 + sRow)) * 768 + sColB;
  const char* bG0 = (const char*)bankbf + ((size_t)(ms * MC + seg0 * 16 + sRow)) * 768 + sColB;
  const char* bG1 = (const char*)bankbf + ((size_t)(ms * MC + seg1 * 16 + sRow)) * 768 + sColB;

  auto stage = [&](int st, int buf) {
    const int kb = (st % 12) * 64;                       // byte offset in row
    const size_t bOff = (size_t)(st / 12) * (BMT * 768); // mtile row block
    glds16(aG0 + kb, &Al[buf][seg0 * 512]);
    glds16(aG1 + kb, &Al[buf][seg1 * 512]);
    glds16(bG0 + bOff + kb, &Bl[buf][seg0 * 512]);
    glds16(bG1 + bOff + kb, &Bl[buf][seg1 * 512]);
  };

  f32x4 acc[4][4];
#pragma unroll
  for (int nf = 0; nf < 4; ++nf)
#pragma unroll
    for (int mf = 0; mf < 4; ++mf) {
      acc[nf][mf][0] = 0.f; acc[nf][mf][1] = 0.f;
      acc[nf][mf][2] = 0.f; acc[nf][mf][3] = 0.f;
    }
  float rm[4][4];
#pragma unroll
  for (int a = 0; a < 4; ++a)
#pragma unroll
    for (int b = 0; b < 4; ++b) rm[a][b] = 3.4e38f;

  stage(0, 0);
  __syncthreads();

  for (int st = 0; st < NSTEPS; ++st) {
    const int buf = st & 1;
    if (st < NSTEPS - 1) stage(st + 1, buf ^ 1);

    bf16x8 af[4], bfr[4];
#pragma unroll
    for (int nf = 0; nf < 4; ++nf)
      af[nf] = *(const bf16x8*)&Al[buf][(wn * 64 + nf * 16 + l15) * 32 + l4 * 8];
#pragma unroll
    for (int mf = 0; mf < 4; ++mf)
      bfr[mf] = *(const bf16x8*)&Bl[buf][(wm * 64 + mf * 16 + l15) * 32 + l4 * 8];
#pragma unroll
    for (int nf = 0; nf < 4; ++nf)
#pragma unroll
      for (int mf = 0; mf < 4; ++mf)
        acc[nf][mf] = __builtin_amdgcn_mfma_f32_16x16x32_bf16(
            af[nf], bfr[mf], acc[nf][mf], 0, 0, 0);

    if ((st % 12) == 11) {  // mtile complete: fold min and reset acc
      const int mt = st / 12;
      const int mb = mt * BMT + wm * 64 + l15;
#pragma unroll
      for (int mf = 0; mf < 4; ++mf) {
        const float yv = ynLds[mb + mf * 16];
#pragma unroll
        for (int nf = 0; nf < 4; ++nf)
#pragma unroll
          for (int r = 0; r < 4; ++r)
            rm[nf][r] = fminf(rm[nf][r], fmaf(-2.f, acc[nf][mf][r], yv));
      }
#pragma unroll
      for (int nf = 0; nf < 4; ++nf)
#pragma unroll
        for (int mf = 0; mf < 4; ++mf) {
          acc[nf][mf][0] = 0.f; acc[nf][mf][1] = 0.f;
          acc[nf][mf][2] = 0.f; acc[nf][mf][3] = 0.f;
        }
    }
    __syncthreads();  // drains prefetch vmcnt + fences buffer reuse
  }

  // per-row min across this wave's 16 column slots; wm halves kept separate
#pragma unroll
  for (int nf = 0; nf < 4; ++nf)
#pragma unroll
    for (int r = 0; r < 4; ++r) {
      float v = rm[nf][r];
      v = fminf(v, __shfl_xor(v, 1, 64));
      v = fminf(v, __shfl_xor(v, 2, 64));
      v = fminf(v, __shfl_xor(v, 4, 64));
      v = fminf(v, __shfl_xor(v, 8, 64));
      if (l15 == 0) {
        const int n = bn * BN + wn * 64 + nf * 16 + l4 * 4 + r;
        psPart[(size_t)n * PSW + ms * 2 + wm] = v;
      }
    }
}

// ------------------------------------------------- reduce 32 partial mins -> patch score
__global__ __launch_bounds__(256) void ps_reduce_kernel(
    const float* __restrict__ psPart, const float* __restrict__ xnorm,
    float* __restrict__ out) {
  const int n = blockIdx.x * 256 + threadIdx.x;
  if (n >= NROWS) return;
  const float4* p = (const float4*)(psPart + (size_t)n * PSW);
  float m = 3.4e38f;
#pragma unroll
  for (int j = 0; j < 8; ++j) {
    const float4 a = p[j];
    m = fminf(m, fminf(fminf(a.x, a.y), fminf(a.z, a.w)));
  }
  out[n] = sqrtf(fmaxf(xnorm[n] + m, 0.f));
}

// ------------------------------------------------- per-batch top-3 rows (noisy ps)
__global__ __launch_bounds__(256) void argmax3_kernel(
    const float* __restrict__ ps, int* __restrict__ trow) {
  __shared__ float vals[PPB];
  __shared__ float sv[256]; __shared__ int si[256];
  const int b = blockIdx.x, t = threadIdx.x;
  for (int p = t; p < PPB; p += 256) vals[p] = ps[b * PPB + p];
  __syncthreads();
  for (int k = 0; k < TOPT; ++k) {
    float best = -3.4e38f; int bi = 0x7FFFFFFF;
    for (int p = t; p < PPB; p += 256) {
      const float v = vals[p];
      if (v > best || (v == best && p < bi)) { best = v; bi = p; }
    }
    sv[t] = best; si[t] = bi;
    __syncthreads();
    for (int s = 128; s > 0; s >>= 1) {
      if (t < s) {
        if (sv[t + s] > sv[t] || (sv[t + s] == sv[t] && si[t + s] < si[t])) {
          sv[t] = sv[t + s]; si[t] = si[t + s];
        }
      }
      __syncthreads();
    }
    if (t == 0) { trow[b * TOPT + k] = b * PPB + si[0]; vals[si[0]] = -3.4e38f; }
    __syncthreads();
  }
}

// ------------------------------------------------- exact rescan for 24 rescue rows
// grid 128 x 256 thr; thread t owns bank row m=bid*256+t; computes yn-2*dot for all 24.
__global__ __launch_bounds__(256) void rescue_kernel(
    const float* __restrict__ emb, const float* __restrict__ bank,
    const float* __restrict__ ynorm, const int* __restrict__ trow,
    float* __restrict__ rscV, int* __restrict__ rscI) {
  __shared__ float xs[NRESC][DDIM];   // 36 KB
  __shared__ int sTrow[NRESC];
  __shared__ float pvw[4][NRESC]; __shared__ int piw[4][NRESC];
  const int t = threadIdx.x, lane = t & 63, wave = t >> 6;
  if (t < NRESC) sTrow[t] = trow[t];
  __syncthreads();
  for (int j = 0; j < NRESC; ++j)
    for (int k = t; k < DDIM; k += 256) xs[j][k] = emb[(size_t)sTrow[j] * DDIM + k];
  __syncthreads();

  const int m = blockIdx.x * 256 + t;
  const float yn = ynorm[m];
  const float* y = bank + (size_t)m * DDIM;
  float accs[NRESC];
#pragma unroll
  for (int j = 0; j < NRESC; ++j) accs[j] = yn;
  for (int k = 0; k < DDIM; ++k) {
    const float bk2 = -2.f * y[k];
#pragma unroll
    for (int j = 0; j < NRESC; ++j) accs[j] = fmaf(bk2, xs[j][k], accs[j]);
  }
  // wave-level (val,idx) min per j, then block partial
#pragma unroll
  for (int j = 0; j < NRESC; ++j) {
    float v = accs[j]; int mi = m;
#pragma unroll
    for (int s = 1; s < 64; s <<= 1) {
      const float ov = __shfl_xor(v, s, 64);
      const int oi = __shfl_xor(mi, s, 64);
      if (ov < v || (ov == v && oi < mi)) { v = ov; mi = oi; }
    }
    if (lane == 0) { pvw[wave][j] = v; piw[wave][j] = mi; }
  }
  __syncthreads();
  if (t < NRESC) {
    float bv = pvw[0][t]; int bi = piw[0][t];
#pragma unroll
    for (int w = 1; w < 4; ++w)
      if (pvw[w][t] < bv || (pvw[w][t] == bv && piw[w][t] < bi)) { bv = pvw[w][t]; bi = piw[w][t]; }
    rscV[(size_t)t * 128 + blockIdx.x] = bv;
    rscI[(size_t)t * 128 + blockIdx.x] = bi;
  }
}

// ------------------------------------------------- merge rescue partials + batch select
__global__ __launch_bounds__(256) void rescue_merge_kernel(
    const float* __restrict__ emb, const int* __restrict__ trow,
    const float* __restrict__ rscV, const int* __restrict__ rscI,
    float* __restrict__ score, int* __restrict__ maxrow, int* __restrict__ nnidx) {
  __shared__ float xnLds[NRESC];
  __shared__ float exv[NRESC]; __shared__ int exi[NRESC];
  const int t = threadIdx.x, lane = t & 63, wave = t >> 6;
  // exact x-norms: wave w handles rows w*6..w*6+5
  for (int q = 0; q < 6; ++q) {
    const int j = wave * 6 + q;
    const float* x = emb + (size_t)trow[j] * DDIM;
    float s = 0.f;
#pragma unroll
    for (int e = 0; e < 6; ++e) { const float v = x[lane + 64 * e]; s = fmaf(v, v, s); }
    s = wredsum(s);
    if (lane == 0) xnLds[j] = s;
  }
  __syncthreads();
  if (t < NRESC) {
    float bv = 3.4e38f; int bi = 0x7FFFFFFF;
    for (int i = 0; i < 128; ++i) {      // ascending block = ascending m (first-idx ties)
      const float v = rscV[(size_t)t * 128 + i];
      if (v < bv) { bv = v; bi = rscI[(size_t)t * 128 + i]; }
      else if (v == bv) { const int oi = rscI[(size_t)t * 128 + i]; if (oi < bi) bi = oi; }
    }
    exv[t] = sqrtf(fmaxf(xnLds[t] + bv, 0.f));
    exi[t] = bi;
  }
  __syncthreads();
  if (t < NB) {
    float best = -3.4e38f; int bj = 0, brow = 0x7FFFFFFF;
    for (int k = 0; k < TOPT; ++k) {
      const int j = t * TOPT + k;
      const int row = trow[j];
      if (exv[j] > best || (exv[j] == best && row < brow)) { best = exv[j]; bj = j; brow = row; }
    }
    score[t] = best; maxrow[t] = brow; nnidx[t] = exi[bj];
  }
}

// ------------------------------------------------- d2: nn_sample vs bank (squared)
__global__ __launch_bounds__(256) void d2_kernel(
    const float* __restrict__ bank, const float* __restrict__ ynorm,
    const int* __restrict__ nnidx, float* __restrict__ d2) {
  __shared__ float nnf[NB][DDIM];
  __shared__ float nno[NB];
  const int t = threadIdx.x;
  for (int b = 0; b < NB; ++b) {
    const int m = nnidx[b];
    for (int j = t; j < DDIM; j += 256) nnf[b][j] = bank[(size_t)m * DDIM + j];
  }
  if (t < NB) nno[t] = ynorm[nnidx[t]];
  __syncthreads();
  const int wave = t >> 6, lane = t & 63;
  const int m = blockIdx.x * 4 + wave;
  const float* y = bank + (size_t)m * DDIM;
  float yv[6];
#pragma unroll
  for (int j = 0; j < 6; ++j) yv[j] = y[lane + 64 * j];
  const float yn = ynorm[m];
  for (int b = 0; b < NB; ++b) {
    float d = 0.f;
#pragma unroll
    for (int j = 0; j < 6; ++j) d = fmaf(yv[j], nnf[b][lane + 64 * j], d);
    d = wredsum(d);
    if (lane == 0) d2[(size_t)b * MROWS + m] = fmaxf(fmaf(-2.f, d, nno[b] + yn), 0.f);
  }
}

// ------------------------------------------------- top-9 phase 1: per-segment top-9
__global__ __launch_bounds__(256) void topk1_kernel(
    const float* __restrict__ d2, float* __restrict__ tv, int* __restrict__ ti) {
  __shared__ float sv[256]; __shared__ int si[256];
  const int b = blockIdx.x / TSEG, seg = blockIdx.x % TSEG;
  const float* base = d2 + (size_t)b * MROWS + seg * 2048;
  const int t = threadIdx.x, off = t * 8;
  float v[8];
  const float4 x0 = *(const float4*)(base + off);
  const float4 x1 = *(const float4*)(base + off + 4);
  v[0] = x0.x; v[1] = x0.y; v[2] = x0.z; v[3] = x0.w;
  v[4] = x1.x; v[5] = x1.y; v[6] = x1.z; v[7] = x1.w;
  for (int k = 0; k < KNN; ++k) {
    float lb = v[0]; int li = 0;
#pragma unroll
    for (int i = 1; i < 8; ++i)
      if (v[i] < lb) { lb = v[i]; li = i; }
    sv[t] = lb; si[t] = off + li;
    __syncthreads();
    for (int s = 128; s > 0; s >>= 1) {
      if (t < s) {
        if (sv[t + s] < sv[t] || (sv[t + s] == sv[t] && si[t + s] < si[t])) {
          sv[t] = sv[t + s]; si[t] = si[t + s];
        }
      }
      __syncthreads();
    }
    const int widx = si[0];
    if (t == 0) {
      tv[(size_t)(b * TSEG + seg) * KNN + k] = sv[0];
      ti[(size_t)(b * TSEG + seg) * KNN + k] = seg * 2048 + widx;
    }
    __syncthreads();
#pragma unroll
    for (int i = 0; i < 8; ++i)
      if (off + i == widx) v[i] = 3.4e38f;
  }
}

// ------------------------------------------------- top-9 phase 2: merge 144 -> 9
__global__ __launch_bounds__(64) void topk2_kernel(
    const float* __restrict__ tv, const int* __restrict__ ti, int* __restrict__ support) {
  const int b = blockIdx.x, lane = threadIdx.x;
  float v[3]; int ix[3];
#pragma unroll
  for (int j = 0; j < 3; ++j) {
    const int e = lane + j * 64;
    if (e < TSEG * KNN) { v[j] = tv[(size_t)b * TSEG * KNN + e]; ix[j] = ti[(size_t)b * TSEG * KNN + e]; }
    else { v[j] = 3.4e38f; ix[j] = 0x7FFFFFFF; }
  }
  for (int k = 0; k < KNN; ++k) {
    float bv = v[0]; int bi = ix[0];
#pragma unroll
    for (int j = 1; j < 3; ++j)
      if (v[j] < bv || (v[j] == bv && ix[j] < bi)) { bv = v[j]; bi = ix[j]; }
#pragma unroll
    for (int m = 1; m < 64; m <<= 1) {
      const float ov = __shfl_xor(bv, m, 64);
      const int oi = __shfl_xor(bi, m, 64);
      if (ov < bv || (ov == bv && oi < bi)) { bv = ov; bi = oi; }
    }
    if (lane == 0) support[b * KNN + k] = bi;
#pragma unroll
    for (int j = 0; j < 3; ++j)
      if (ix[j] == bi) v[j] = 3.4e38f;
  }
}

// ------------------------------------------------- d3 + softmax + pred_score
__global__ __launch_bounds__(256) void final_kernel(
    const float* __restrict__ emb, const float* __restrict__ bank,
    const float* __restrict__ ynorm, const int* __restrict__ support,
    const int* __restrict__ maxrow, const float* __restrict__ score,
    float* __restrict__ pred) {
  __shared__ float d3s[NB][KNN];
  const int t = threadIdx.x, wave = t >> 6, lane = t & 63;
  for (int b = wave; b < NB; b += 4) {
    const float* x = emb + (size_t)maxrow[b] * DDIM;
    float xv[6];
#pragma unroll
    for (int j = 0; j < 6; ++j) xv[j] = x[lane + 64 * j];
    float xn = 0.f;
#pragma unroll
    for (int j = 0; j < 6; ++j) xn = fmaf(xv[j], xv[j], xn);
    xn = wredsum(xn);
    for (int k = 0; k < KNN; ++k) {
      const int m = support[b * KNN + k];
      const float* y = bank + (size_t)m * DDIM;
      float d = 0.f;
#pragma unroll
      for (int j = 0; j < 6; ++j) d = fmaf(xv[j], y[lane + 64 * j], d);
      d = wredsum(d);
      if (lane == 0) d3s[b][k] = sqrtf(fmaxf(fmaf(-2.f, d, xn + ynorm[m]), 0.f));
    }
  }
  __syncthreads();
  if (t < NB) {
    float mx = -3.4e38f;
    for (int k = 0; k < KNN; ++k) mx = fmaxf(mx, d3s[t][k]);
    float sum = 0.f, e0 = 0.f;
    for (int k = 0; k < KNN; ++k) {
      const float e = expf(d3s[t][k] - mx);
      if (k == 0) e0 = e;
      sum += e;
    }
    pred[t] = (1.f - e0 / sum) * score[t];
  }
}

extern "C" void kernel_launch(void* const* d_in, const int* in_sizes, int n_in,
                              void* d_out, int out_size, void* d_ws, size_t ws_size,
                              hipStream_t stream) {
  (void)in_sizes; (void)n_in; (void)out_size; (void)ws_size;
  const float* emb = (const float*)d_in[0];
  const float* bank = (const float*)d_in[1];
  float* out = (float*)d_out;

  char* ws = (char*)d_ws;
  size_t o = 0;
  auto alloc = [&](size_t bytes) { void* p = ws + o; o = (o + bytes + 255) & ~(size_t)255; return p; };
  float* ynorm = (float*)alloc((size_t)MROWS * 4);
  float* xnorm = (float*)alloc((size_t)NROWS * 4);
  unsigned short* embbf = (unsigned short*)alloc((size_t)NROWS * DDIM * 2);
  unsigned short* bankbf = (unsigned short*)alloc((size_t)MROWS * DDIM * 2);
  float* psPart = (float*)alloc((size_t)NROWS * PSW * 4);
  int* trow = (int*)alloc(NRESC * 4);
  float* rscV = (float*)alloc((size_t)NRESC * 128 * 4);
  int* rscI = (int*)alloc((size_t)NRESC * 128 * 4);
  float* d2 = (float*)alloc((size_t)NB * MROWS * 4);
  float* tv = (float*)alloc((size_t)NB * TSEG * KNN * 4);
  int* ti = (int*)alloc((size_t)NB * TSEG * KNN * 4);
  float* score = (float*)alloc(256);
  int* maxrow = (int*)alloc(256);
  int* nnidx = (int*)alloc(256);
  int* support = (int*)alloc(512);

  cvt_bf16_kernel<<<NROWS * DDIM / 8 / 256, 256, 0, stream>>>(emb, embbf);
  cvt_bf16_kernel<<<MROWS * DDIM / 8 / 256, 256, 0, stream>>>(bank, bankbf);
  rownorm_kernel<<<MROWS / 4, 256, 0, stream>>>(bank, ynorm);
  rownorm_kernel<<<NROWS / 4, 256, 0, stream>>>(emb, xnorm);
  dist_min_kernel<<<(NROWS / BN) * MSPLIT, 256, 0, stream>>>(embbf, bankbf, ynorm, psPart);
  ps_reduce_kernel<<<(NROWS + 255) / 256, 256, 0, stream>>>(psPart, xnorm, out);
  argmax3_kernel<<<NB, 256, 0, stream>>>(out, trow);
  rescue_kernel<<<MROWS / 256, 256, 0, stream>>>(emb, bank, ynorm, trow, rscV, rscI);
  rescue_merge_kernel<<<1, 256, 0, stream>>>(emb, trow, rscV, rscI, score, maxrow, nnidx);
  d2_kernel<<<MROWS / 4, 256, 0, stream>>>(bank, ynorm, nnidx, d2);
  topk1_kernel<<<NB * TSEG, 256, 0, stream>>>(d2, tv, ti);
  topk2_kernel<<<NB, 64, 0, stream>>>(tv, ti, support);
  final_kernel<<<1, 256, 0, stream>>>(emb, bank, ynorm, support, maxrow, score, out + NROWS);
}

// Round 9
// 566.698 us; speedup vs baseline: 1.1019x; 1.1019x over previous
//
#include <hip/hip_runtime.h>
#include <hip/hip_bf16.h>

#define NROWS 6272
#define MROWS 32768
#define DDIM  384
#define NB    8
#define PPB   784
#define BN    128
#define BMT   128
#define MSPLIT 32
#define MC    (MROWS / MSPLIT)     // 1024
#define MTILES (MC / BMT)          // 8
#define NSTEPS (MTILES * 12)       // 96 K-steps of 32
#define PSW   (MSPLIT * 2)         // 64 partial slots per row (chunk x wm-half)
#define KNN   9
#define TSEG  16
#define TOPT  4
#define NRESC (NB * TOPT)          // 32
#define NPART 2048                 // rescue partial blocks (MROWS/16)

typedef float f32x4 __attribute__((ext_vector_type(4)));
typedef short bf16x8 __attribute__((ext_vector_type(8)));

__device__ __forceinline__ unsigned short f2bf(float f) {
  union { float f; unsigned int u; } c; c.f = f;
  unsigned int u = c.u + 0x7FFFu + ((c.u >> 16) & 1u);  // RNE
  return (unsigned short)(u >> 16);
}
__device__ __forceinline__ unsigned int pk2(float a, float b) {
  return (unsigned int)f2bf(a) | ((unsigned int)f2bf(b) << 16);
}
__device__ __forceinline__ float wredsum(float v) {
#pragma unroll
  for (int m = 32; m; m >>= 1) v += __shfl_xor(v, m, 64);
  return v;
}
__device__ __forceinline__ void glds16(const void* g, void* l) {
  __builtin_amdgcn_global_load_lds(
      (const __attribute__((address_space(1))) unsigned int*)g,
      (__attribute__((address_space(3))) unsigned int*)l, 16, 0, 0);
}

// ---------------------------------------------------------------- fp32 -> bf16 copy
__global__ __launch_bounds__(256) void cvt_bf16_kernel(
    const float* __restrict__ src, unsigned short* __restrict__ dst) {
  const int i = blockIdx.x * 256 + threadIdx.x;  // 8 elems per thread
  const float4 a = ((const float4*)src)[i * 2];
  const float4 b = ((const float4*)src)[i * 2 + 1];
  uint4 o = { pk2(a.x, a.y), pk2(a.z, a.w), pk2(b.x, b.y), pk2(b.z, b.w) };
  ((uint4*)dst)[i] = o;
}

// ---------------------------------------------------------------- row norms (exact fp32)
__global__ __launch_bounds__(256) void rownorm_kernel(
    const float* __restrict__ src, float* __restrict__ nrm) {
  const int wave = threadIdx.x >> 6, lane = threadIdx.x & 63;
  const int m = blockIdx.x * 4 + wave;
  const float* y = src + (size_t)m * DDIM;
  float s = 0.f;
#pragma unroll
  for (int j = 0; j < 6; ++j) { float v = y[lane + 64 * j]; s = fmaf(v, v, s); }
  s = wredsum(s);
  if (lane == 0) nrm[m] = s;
}

// ------------------------------------------------- hot: bf16 MFMA per-chunk min
// grid 1568; ms = bid&31 (ms%8 == bid%8 -> XCD-affine, chunk L2-resident).
// Double-buffered LDS, one barrier/step. LDS layout swizzled (rule21-safe):
// linear gload_lds dest + inverse-swizzled GLOBAL source + swizzled ds_read:
// 16B slot s of row r holds global slot s^((r&15)>>1&3) -> 8-way -> 2-way (free).
__global__ __launch_bounds__(256) void dist_min_kernel(
    const unsigned short* __restrict__ embbf, const unsigned short* __restrict__ bankbf,
    const float* __restrict__ ynorm, float* __restrict__ psPart) {
  __shared__ unsigned short Al[2][4096];   // [buf][128 rows x 32 bf16] 64B rows
  __shared__ unsigned short Bl[2][4096];

  const int bid = blockIdx.x;
  const int ms = bid & (MSPLIT - 1);
  const int bn = bid >> 5;
  const int t = threadIdx.x;
  const int lane = t & 63;
  const int wave = t >> 6;
  const int wn = wave >> 1, wm = wave & 1;
  const int l15 = lane & 15, l4 = lane >> 4;

  // staging sources, pre-swizzled (global_load_lds dest = uniform base + lane*16B)
  const int seg0 = wave * 2, seg1 = seg0 + 1;
  const int sRow = lane >> 2;
  const int srcSlot = (lane & 3) ^ ((sRow >> 1) & 3);
  const int sColB = srcSlot * 16;  // bytes
  const char* aG0 = (const char*)embbf + ((size_t)(bn * BN + seg0 * 16 + sRow)) * 768 + sColB;
  const char* aG1 = (const char*)embbf + ((size_t)(bn * BN + seg1 * 16 + sRow)) * 768 + sColB;
  const char* bG0 = (const char*)bankbf + ((size_t)(ms * MC + seg0 * 16 + sRow)) * 768 + sColB;
  const char* bG1 = (const char*)bankbf + ((size_t)(ms * MC + seg1 * 16 + sRow)) * 768 + sColB;

  auto stage = [&](int st, int buf) {
    const int kb = (st % 12) * 64;                       // byte offset in row
    const size_t bOff = (size_t)(st / 12) * (BMT * 768); // mtile row block
    glds16(aG0 + kb, &Al[buf][seg0 * 512]);
    glds16(aG1 + kb, &Al[buf][seg1 * 512]);
    glds16(bG0 + bOff + kb, &Bl[buf][seg0 * 512]);
    glds16(bG1 + bOff + kb, &Bl[buf][seg1 * 512]);
  };

  // swizzled read slot (bf16 elem index): rows read are base+l15 -> rowInSeg=l15
  const int rdSlot = (l4 ^ ((l15 >> 1) & 3)) * 8;

  f32x4 acc[4][4];
#pragma unroll
  for (int nf = 0; nf < 4; ++nf)
#pragma unroll
    for (int mf = 0; mf < 4; ++mf) {
      acc[nf][mf][0] = 0.f; acc[nf][mf][1] = 0.f;
      acc[nf][mf][2] = 0.f; acc[nf][mf][3] = 0.f;
    }
  float rm[4][4];
#pragma unroll
  for (int a = 0; a < 4; ++a)
#pragma unroll
    for (int b = 0; b < 4; ++b) rm[a][b] = 3.4e38f;

  const float* ynG = ynorm + ms * MC;

  stage(0, 0);
  __syncthreads();

  for (int st = 0; st < NSTEPS; ++st) {
    const int buf = st & 1;
    if (st < NSTEPS - 1) stage(st + 1, buf ^ 1);

    bf16x8 af[4], bfr[4];
#pragma unroll
    for (int nf = 0; nf < 4; ++nf)
      af[nf] = *(const bf16x8*)&Al[buf][(wn * 64 + nf * 16 + l15) * 32 + rdSlot];
#pragma unroll
    for (int mf = 0; mf < 4; ++mf)
      bfr[mf] = *(const bf16x8*)&Bl[buf][(wm * 64 + mf * 16 + l15) * 32 + rdSlot];
#pragma unroll
    for (int nf = 0; nf < 4; ++nf)
#pragma unroll
      for (int mf = 0; mf < 4; ++mf)
        acc[nf][mf] = __builtin_amdgcn_mfma_f32_16x16x32_bf16(
            af[nf], bfr[mf], acc[nf][mf], 0, 0, 0);

    if ((st % 12) == 11) {  // mtile complete: fold min and reset acc
      const int mt = st / 12;
      const int mb = mt * BMT + wm * 64 + l15;
#pragma unroll
      for (int mf = 0; mf < 4; ++mf) {
        const float yv = ynG[mb + mf * 16];
#pragma unroll
        for (int nf = 0; nf < 4; ++nf)
#pragma unroll
          for (int r = 0; r < 4; ++r)
            rm[nf][r] = fminf(rm[nf][r], fmaf(-2.f, acc[nf][mf][r], yv));
      }
#pragma unroll
      for (int nf = 0; nf < 4; ++nf)
#pragma unroll
        for (int mf = 0; mf < 4; ++mf) {
          acc[nf][mf][0] = 0.f; acc[nf][mf][1] = 0.f;
          acc[nf][mf][2] = 0.f; acc[nf][mf][3] = 0.f;
        }
    }
    __syncthreads();  // drains prefetch vmcnt + fences buffer reuse
  }

  // per-row min across this wave's 16 column slots; wm halves kept separate
#pragma unroll
  for (int nf = 0; nf < 4; ++nf)
#pragma unroll
    for (int r = 0; r < 4; ++r) {
      float v = rm[nf][r];
      v = fminf(v, __shfl_xor(v, 1, 64));
      v = fminf(v, __shfl_xor(v, 2, 64));
      v = fminf(v, __shfl_xor(v, 4, 64));
      v = fminf(v, __shfl_xor(v, 8, 64));
      if (l15 == 0) {
        const int n = bn * BN + wn * 64 + nf * 16 + l4 * 4 + r;
        psPart[(size_t)n * PSW + ms * 2 + wm] = v;
      }
    }
}

// ------------------------------------------------- reduce 64 partial mins -> patch score
__global__ __launch_bounds__(256) void ps_reduce_kernel(
    const float* __restrict__ psPart, const float* __restrict__ xnorm,
    float* __restrict__ out) {
  const int n = blockIdx.x * 256 + threadIdx.x;
  if (n >= NROWS) return;
  const float4* p = (const float4*)(psPart + (size_t)n * PSW);
  float m = 3.4e38f;
#pragma unroll
  for (int j = 0; j < PSW / 4; ++j) {
    const float4 a = p[j];
    m = fminf(m, fminf(fminf(a.x, a.y), fminf(a.z, a.w)));
  }
  out[n] = sqrtf(fmaxf(xnorm[n] + m, 0.f));
}

// ------------------------------------------------- per-batch top-4 rows (noisy ps)
__global__ __launch_bounds__(256) void argmax4_kernel(
    const float* __restrict__ ps, int* __restrict__ trow) {
  __shared__ float vals[PPB];
  __shared__ float sv[256]; __shared__ int si[256];
  const int b = blockIdx.x, t = threadIdx.x;
  for (int p = t; p < PPB; p += 256) vals[p] = ps[b * PPB + p];
  __syncthreads();
  for (int k = 0; k < TOPT; ++k) {
    float best = -3.4e38f; int bi = 0x7FFFFFFF;
    for (int p = t; p < PPB; p += 256) {
      const float v = vals[p];
      if (v > best || (v == best && p < bi)) { best = v; bi = p; }
    }
    sv[t] = best; si[t] = bi;
    __syncthreads();
    for (int s = 128; s > 0; s >>= 1) {
      if (t < s) {
        if (sv[t + s] > sv[t] || (sv[t + s] == sv[t] && si[t + s] < si[t])) {
          sv[t] = sv[t + s]; si[t] = si[t + s];
        }
      }
      __syncthreads();
    }
    if (t == 0) { trow[b * TOPT + k] = b * PPB + si[0]; vals[si[0]] = -3.4e38f; }
    __syncthreads();
  }
}

// ------------------------------------------------- exact rescan for 32 rescue rows
// d2-style coalesced: grid NPART=2048; 4 waves x 4 bank rows each; 32 x-rows in LDS.
__global__ __launch_bounds__(256) void rescue_kernel(
    const float* __restrict__ emb, const float* __restrict__ bank,
    const float* __restrict__ ynorm, const int* __restrict__ trow,
    float* __restrict__ rscV, int* __restrict__ rscI) {
  __shared__ float xs[NRESC * DDIM];   // 48 KB
  __shared__ int sTrow[NRESC];
  __shared__ float pvw[4][NRESC]; __shared__ int piw[4][NRESC];
  const int t = threadIdx.x, lane = t & 63, wave = t >> 6;
  if (t < NRESC) sTrow[t] = trow[t];
  __syncthreads();
  // stage 32 x-rows (float4, coalesced within each row)
  for (int idx = t; idx < NRESC * (DDIM / 4); idx += 256) {
    const int j = idx / (DDIM / 4), c = idx % (DDIM / 4);
    ((float4*)xs)[idx] = ((const float4*)(emb + (size_t)sTrow[j] * DDIM))[c];
  }
  __syncthreads();

  // this wave's 4 bank rows (coalesced loads)
  const int m0 = blockIdx.x * 16 + wave * 4;
  float yv[4][6]; float yn[4];
#pragma unroll
  for (int q = 0; q < 4; ++q) {
    const float* y = bank + (size_t)(m0 + q) * DDIM;
#pragma unroll
    for (int e = 0; e < 6; ++e) yv[q][e] = y[lane + 64 * e];
    yn[q] = ynorm[m0 + q];
  }

  for (int j = 0; j < NRESC; ++j) {
    float s0 = 0.f, s1 = 0.f, s2 = 0.f, s3 = 0.f;
#pragma unroll
    for (int e = 0; e < 6; ++e) {
      const float xe = xs[j * DDIM + lane + 64 * e];
      s0 = fmaf(yv[0][e], xe, s0);
      s1 = fmaf(yv[1][e], xe, s1);
      s2 = fmaf(yv[2][e], xe, s2);
      s3 = fmaf(yv[3][e], xe, s3);
    }
    s0 = wredsum(s0); s1 = wredsum(s1); s2 = wredsum(s2); s3 = wredsum(s3);
    // min over 4 rows, first-index ties
    float bv = fmaf(-2.f, s0, yn[0]); int bi = m0;
    float v1 = fmaf(-2.f, s1, yn[1]); if (v1 < bv) { bv = v1; bi = m0 + 1; }
    float v2 = fmaf(-2.f, s2, yn[2]); if (v2 < bv) { bv = v2; bi = m0 + 2; }
    float v3 = fmaf(-2.f, s3, yn[3]); if (v3 < bv) { bv = v3; bi = m0 + 3; }
    if (lane == 0) { pvw[wave][j] = bv; piw[wave][j] = bi; }
  }
  __syncthreads();
  if (t < NRESC) {
    float bv = pvw[0][t]; int bi = piw[0][t];
#pragma unroll
    for (int w = 1; w < 4; ++w)
      if (pvw[w][t] < bv || (pvw[w][t] == bv && piw[w][t] < bi)) { bv = pvw[w][t]; bi = piw[w][t]; }
    rscV[(size_t)t * NPART + blockIdx.x] = bv;
    rscI[(size_t)t * NPART + blockIdx.x] = bi;
  }
}

// ------------------------------------------------- merge rescue partials + batch select
__global__ __launch_bounds__(256) void rescue_merge_kernel(
    const float* __restrict__ emb, const int* __restrict__ trow,
    const float* __restrict__ rscV, const int* __restrict__ rscI,
    float* __restrict__ score, int* __restrict__ maxrow, int* __restrict__ nnidx) {
  __shared__ float mv[NRESC][8]; __shared__ int mi[NRESC][8];
  __shared__ float xnLds[NRESC];
  __shared__ float exv[NRESC]; __shared__ int exi[NRESC];
  const int t = threadIdx.x, lane = t & 63, wave = t >> 6;
  // phase 1: j = t>>3, slice = t&7 over NPART
  {
    const int j = t >> 3, sl = t & 7;
    float bv = 3.4e38f; int bi = 0x7FFFFFFF;
    for (int i = sl * (NPART / 8); i < (sl + 1) * (NPART / 8); ++i) {
      const float v = rscV[(size_t)j * NPART + i];
      if (v < bv) { bv = v; bi = rscI[(size_t)j * NPART + i]; }
      else if (v == bv) { const int oi = rscI[(size_t)j * NPART + i]; if (oi < bi) bi = oi; }
    }
    mv[j][sl] = bv; mi[j][sl] = bi;
  }
  // exact x-norms: wave w rows w*8..w*8+7
  for (int q = 0; q < 8; ++q) {
    const int j = wave * 8 + q;
    const float* x = emb + (size_t)trow[j] * DDIM;
    float s = 0.f;
#pragma unroll
    for (int e = 0; e < 6; ++e) { const float v = x[lane + 64 * e]; s = fmaf(v, v, s); }
    s = wredsum(s);
    if (lane == 0) xnLds[j] = s;
  }
  __syncthreads();
  if (t < NRESC) {
    float bv = mv[t][0]; int bi = mi[t][0];
#pragma unroll
    for (int s = 1; s < 8; ++s)
      if (mv[t][s] < bv || (mv[t][s] == bv && mi[t][s] < bi)) { bv = mv[t][s]; bi = mi[t][s]; }
    exv[t] = sqrtf(fmaxf(xnLds[t] + bv, 0.f));
    exi[t] = bi;
  }
  __syncthreads();
  if (t < NB) {
    float best = -3.4e38f; int bj = 0, brow = 0x7FFFFFFF;
    for (int k = 0; k < TOPT; ++k) {
      const int j = t * TOPT + k;
      const int row = trow[j];
      if (exv[j] > best || (exv[j] == best && row < brow)) { best = exv[j]; bj = j; brow = row; }
    }
    score[t] = best; maxrow[t] = brow; nnidx[t] = exi[bj];
  }
}

// ------------------------------------------------- d2: nn_sample vs bank (squared)
__global__ __launch_bounds__(256) void d2_kernel(
    const float* __restrict__ bank, const float* __restrict__ ynorm,
    const int* __restrict__ nnidx, float* __restrict__ d2) {
  __shared__ float nnf[NB][DDIM];
  __shared__ float nno[NB];
  const int t = threadIdx.x;
  for (int b = 0; b < NB; ++b) {
    const int m = nnidx[b];
    for (int j = t; j < DDIM; j += 256) nnf[b][j] = bank[(size_t)m * DDIM + j];
  }
  if (t < NB) nno[t] = ynorm[nnidx[t]];
  __syncthreads();
  const int wave = t >> 6, lane = t & 63;
  const int m = blockIdx.x * 4 + wave;
  const float* y = bank + (size_t)m * DDIM;
  float yv[6];
#pragma unroll
  for (int j = 0; j < 6; ++j) yv[j] = y[lane + 64 * j];
  const float yn = ynorm[m];
  for (int b = 0; b < NB; ++b) {
    float d = 0.f;
#pragma unroll
    for (int j = 0; j < 6; ++j) d = fmaf(yv[j], nnf[b][lane + 64 * j], d);
    d = wredsum(d);
    if (lane == 0) d2[(size_t)b * MROWS + m] = fmaxf(fmaf(-2.f, d, nno[b] + yn), 0.f);
  }
}

// ------------------------------------------------- top-9 phase 1: per-segment top-9
__global__ __launch_bounds__(256) void topk1_kernel(
    const float* __restrict__ d2, float* __restrict__ tv, int* __restrict__ ti) {
  __shared__ float sv[256]; __shared__ int si[256];
  const int b = blockIdx.x / TSEG, seg = blockIdx.x % TSEG;
  const float* base = d2 + (size_t)b * MROWS + seg * 2048;
  const int t = threadIdx.x, off = t * 8;
  float v[8];
  const float4 x0 = *(const float4*)(base + off);
  const float4 x1 = *(const float4*)(base + off + 4);
  v[0] = x0.x; v[1] = x0.y; v[2] = x0.z; v[3] = x0.w;
  v[4] = x1.x; v[5] = x1.y; v[6] = x1.z; v[7] = x1.w;
  for (int k = 0; k < KNN; ++k) {
    float lb = v[0]; int li = 0;
#pragma unroll
    for (int i = 1; i < 8; ++i)
      if (v[i] < lb) { lb = v[i]; li = i; }
    sv[t] = lb; si[t] = off + li;
    __syncthreads();
    for (int s = 128; s > 0; s >>= 1) {
      if (t < s) {
        if (sv[t + s] < sv[t] || (sv[t + s] == sv[t] && si[t + s] < si[t])) {
          sv[t] = sv[t + s]; si[t] = si[t + s];
        }
      }
      __syncthreads();
    }
    const int widx = si[0];
    if (t == 0) {
      tv[(size_t)(b * TSEG + seg) * KNN + k] = sv[0];
      ti[(size_t)(b * TSEG + seg) * KNN + k] = seg * 2048 + widx;
    }
    __syncthreads();
#pragma unroll
    for (int i = 0; i < 8; ++i)
      if (off + i == widx) v[i] = 3.4e38f;
  }
}

// ------------------------------------------------- top-9 phase 2: merge 144 -> 9
__global__ __launch_bounds__(64) void topk2_kernel(
    const float* __restrict__ tv, const int* __restrict__ ti, int* __restrict__ support) {
  const int b = blockIdx.x, lane = threadIdx.x;
  float v[3]; int ix[3];
#pragma unroll
  for (int j = 0; j < 3; ++j) {
    const int e = lane + j * 64;
    if (e < TSEG * KNN) { v[j] = tv[(size_t)b * TSEG * KNN + e]; ix[j] = ti[(size_t)b * TSEG * KNN + e]; }
    else { v[j] = 3.4e38f; ix[j] = 0x7FFFFFFF; }
  }
  for (int k = 0; k < KNN; ++k) {
    float bv = v[0]; int bi = ix[0];
#pragma unroll
    for (int j = 1; j < 3; ++j)
      if (v[j] < bv || (v[j] == bv && ix[j] < bi)) { bv = v[j]; bi = ix[j]; }
#pragma unroll
    for (int m = 1; m < 64; m <<= 1) {
      const float ov = __shfl_xor(bv, m, 64);
      const int oi = __shfl_xor(bi, m, 64);
      if (ov < bv || (ov == bv && oi < bi)) { bv = ov; bi = oi; }
    }
    if (lane == 0) support[b * KNN + k] = bi;
#pragma unroll
    for (int j = 0; j < 3; ++j)
      if (ix[j] == bi) v[j] = 3.4e38f;
  }
}

// ------------------------------------------------- d3 + softmax + pred_score
__global__ __launch_bounds__(256) void final_kernel(
    const float* __restrict__ emb, const float* __restrict__ bank,
    const float* __restrict__ ynorm, const int* __restrict__ support,
    const int* __restrict__ maxrow, const float* __restrict__ score,
    float* __restrict__ pred) {
  __shared__ float d3s[NB][KNN];
  const int t = threadIdx.x, wave = t >> 6, lane = t & 63;
  for (int b = wave; b < NB; b += 4) {
    const float* x = emb + (size_t)maxrow[b] * DDIM;
    float xv[6];
#pragma unroll
    for (int j = 0; j < 6; ++j) xv[j] = x[lane + 64 * j];
    float xn = 0.f;
#pragma unroll
    for (int j = 0; j < 6; ++j) xn = fmaf(xv[j], xv[j], xn);
    xn = wredsum(xn);
    for (int k = 0; k < KNN; ++k) {
      const int m = support[b * KNN + k];
      const float* y = bank + (size_t)m * DDIM;
      float d = 0.f;
#pragma unroll
      for (int j = 0; j < 6; ++j) d = fmaf(xv[j], y[lane + 64 * j], d);
      d = wredsum(d);
      if (lane == 0) d3s[b][k] = sqrtf(fmaxf(fmaf(-2.f, d, xn + ynorm[m]), 0.f));
    }
  }
  __syncthreads();
  if (t < NB) {
    float mx = -3.4e38f;
    for (int k = 0; k < KNN; ++k) mx = fmaxf(mx, d3s[t][k]);
    float sum = 0.f, e0 = 0.f;
    for (int k = 0; k < KNN; ++k) {
      const float e = expf(d3s[t][k] - mx);
      if (k == 0) e0 = e;
      sum += e;
    }
    pred[t] = (1.f - e0 / sum) * score[t];
  }
}

extern "C" void kernel_launch(void* const* d_in, const int* in_sizes, int n_in,
                              void* d_out, int out_size, void* d_ws, size_t ws_size,
                              hipStream_t stream) {
  (void)in_sizes; (void)n_in; (void)out_size; (void)ws_size;
  const float* emb = (const float*)d_in[0];
  const float* bank = (const float*)d_in[1];
  float* out = (float*)d_out;

  char* ws = (char*)d_ws;
  size_t o = 0;
  auto alloc = [&](size_t bytes) { void* p = ws + o; o = (o + bytes + 255) & ~(size_t)255; return p; };
  float* ynorm = (float*)alloc((size_t)MROWS * 4);
  float* xnorm = (float*)alloc((size_t)NROWS * 4);
  unsigned short* embbf = (unsigned short*)alloc((size_t)NROWS * DDIM * 2);
  unsigned short* bankbf = (unsigned short*)alloc((size_t)MROWS * DDIM * 2);
  float* psPart = (float*)alloc((size_t)NROWS * PSW * 4);
  int* trow = (int*)alloc(NRESC * 4);
  float* rscV = (float*)alloc((size_t)NRESC * NPART * 4);
  int* rscI = (int*)alloc((size_t)NRESC * NPART * 4);
  float* d2 = (float*)alloc((size_t)NB * MROWS * 4);
  float* tv = (float*)alloc((size_t)NB * TSEG * KNN * 4);
  int* ti = (int*)alloc((size_t)NB * TSEG * KNN * 4);
  float* score = (float*)alloc(256);
  int* maxrow = (int*)alloc(256);
  int* nnidx = (int*)alloc(256);
  int* support = (int*)alloc(512);

  cvt_bf16_kernel<<<NROWS * DDIM / 8 / 256, 256, 0, stream>>>(emb, embbf);
  cvt_bf16_kernel<<<MROWS * DDIM / 8 / 256, 256, 0, stream>>>(bank, bankbf);
  rownorm_kernel<<<MROWS / 4, 256, 0, stream>>>(bank, ynorm);
  rownorm_kernel<<<NROWS / 4, 256, 0, stream>>>(emb, xnorm);
  dist_min_kernel<<<(NROWS / BN) * MSPLIT, 256, 0, stream>>>(embbf, bankbf, ynorm, psPart);
  ps_reduce_kernel<<<(NROWS + 255) / 256, 256, 0, stream>>>(psPart, xnorm, out);
  argmax4_kernel<<<NB, 256, 0, stream>>>(out, trow);
  rescue_kernel<<<NPART, 256, 0, stream>>>(emb, bank, ynorm, trow, rscV, rscI);
  rescue_merge_kernel<<<1, 256, 0, stream>>>(emb, trow, rscV, rscI, score, maxrow, nnidx);
  d2_kernel<<<MROWS / 4, 256, 0, stream>>>(bank, ynorm, nnidx, d2);
  topk1_kernel<<<NB * TSEG, 256, 0, stream>>>(d2, tv, ti);
  topk2_kernel<<<NB, 64, 0, stream>>>(tv, ti, support);
  final_kernel<<<1, 256, 0, stream>>>(emb, bank, ynorm, support, maxrow, score, out + NROWS);
}